// Round 8
// baseline (1265.689 us; speedup 1.0000x reference)
//
#include <hip/hip_runtime.h>

#define HG 200
#define WGR 704
#define CC 256
#define NBOX 128

typedef unsigned short u16;
typedef __attribute__((ext_vector_type(8))) short short8;
typedef __attribute__((ext_vector_type(4))) short short4v;
typedef __attribute__((ext_vector_type(4))) float floatx4;

typedef __attribute__((address_space(1))) const unsigned int guint;
typedef __attribute__((address_space(3))) unsigned int luint;

__device__ __forceinline__ float bf2f(u16 u) {
  unsigned int x = ((unsigned int)u) << 16;
  return __builtin_bit_cast(float, x);
}
__device__ __forceinline__ u16 f2bf(float f) {
  unsigned int x = __builtin_bit_cast(unsigned int, f);
  x += 0x7fffu + ((x >> 16) & 1u);  // round-to-nearest-even
  return (u16)(x >> 16);
}

// ---------------- weight repack + fp32->bf16 ----------------
// Layout (round-0/2 proven): [conv][tap][ck(8)][cogrp(16)][lane(64)][8]:
//   co = cogrp*16 + (l&15), ci = ck*32 + (l>>4)*8 + j
// => a wave's 16co x 32ci B-fragment is ONE contiguous 1KB block (lane*16B).
__global__ __launch_bounds__(256) void pack_w_kernel(const float* __restrict__ cw, u16* __restrict__ W2) {
  int i = blockIdx.x * 256 + threadIdx.x;  // < 6*9*256*256 = 3,538,944
  int conv = i / 589824;
  int r = i - conv * 589824;
  int tap = r / 65536;
  int r2 = r - tap * 65536;
  int ck = r2 >> 13;
  int r3 = r2 & 8191;
  int cogrp = r3 >> 9;
  int r4 = r3 & 511;
  int lane = r4 >> 3;
  int j = r4 & 7;
  int co = cogrp * 16 + (lane & 15);
  int ci = ck * 32 + (lane >> 4) * 8 + j;
  W2[i] = f2bf(cw[((conv * 256 + co) * 256 + ci) * 9 + tap]);
}

// ---------------- BN fold ----------------
__global__ __launch_bounds__(256) void bn_prep_kernel(const float* __restrict__ g, const float* __restrict__ b,
                                                      const float* __restrict__ m, const float* __restrict__ v,
                                                      float* __restrict__ binv, float* __restrict__ bbias) {
  int i = blockIdx.x * 256 + threadIdx.x;  // < 6*256
  float inv = g[i] / sqrtf(v[i] + 1e-5f);
  binv[i] = inv;
  bbias[i] = b[i] - m[i] * inv;
}

// ---------------- box geometry (f32 bit-exact vs reference) ----------------
__global__ __launch_bounds__(128) void box_prep_kernel(const float* __restrict__ pb, float* __restrict__ geo) {
  int b = threadIdx.x;
  float gx[4], gy[4];
#pragma unroll
  for (int j = 0; j < 4; ++j) {
    float px = pb[(b * 8 + j) * 3 + 0];
    float py = pb[(b * 8 + j) * 3 + 1];
    gx[j] = __fdiv_rn(__fsub_rn(px, -140.8f), 0.4f);
    gy[j] = __fdiv_rn(__fsub_rn(py, -40.0f), 0.4f);
  }
  float* g = geo + b * 16;
#pragma unroll
  for (int e = 0; e < 4; ++e) {
    g[e * 4 + 0] = gx[e];
    g[e * 4 + 1] = gy[e];
    g[e * 4 + 2] = __fsub_rn(gx[(e + 1) & 3], gx[e]);
    g[e * 4 + 3] = __fsub_rn(gy[(e + 1) & 3], gy[e]);
  }
}

// ---------------- MLP: one block per box ----------------
__global__ __launch_bounds__(256) void mlp_kernel(
    const float* __restrict__ pb, const float* __restrict__ score,
    const float* __restrict__ w1, const float* __restrict__ b1,
    const float* __restrict__ w2, const float* __restrict__ b2,
    const float* __restrict__ w3, const float* __restrict__ b3,
    float* __restrict__ obj) {
  __shared__ float sf[25];
  __shared__ float h1[256];
  __shared__ float h2[256];
  int b = blockIdx.x, t = threadIdx.x;
  if (t < 24) sf[t] = pb[b * 24 + t];
  if (t == 24) sf[24] = score[b];
  __syncthreads();
  float a = b1[t];
  for (int k = 0; k < 25; ++k) a += sf[k] * w1[k * 256 + t];
  h1[t] = fmaxf(a, 0.0f);
  __syncthreads();
  a = b2[t];
  for (int k = 0; k < 256; ++k) a += h1[k] * w2[k * 256 + t];
  h2[t] = fmaxf(a, 0.0f);
  __syncthreads();
  a = b3[t];
  for (int k = 0; k < 256; ++k) a += h2[k] * w3[k * 256 + t];
  obj[b * 256 + t] = a * score[b];
}

// ---------------- raster (gather): one wave per cell ----------------
__global__ __launch_bounds__(256) void raster_kernel(
    const float* __restrict__ geo, const float* __restrict__ obj, u16* __restrict__ x0) {
  __shared__ float sG[NBOX * 17];
  int tid = threadIdx.x;
  for (int i = tid; i < NBOX * 16; i += 256) sG[(i >> 4) * 17 + (i & 15)] = geo[i];
  __syncthreads();
  int wid = tid >> 6, lane = tid & 63;
  int cell = blockIdx.x * 4 + wid;  // 35200*4 = 140800
  int h = cell / WGR, w = cell - h * WGR;
  float cx = w + 0.5f, cy = h + 0.5f;

  auto test = [&](int n) -> bool {
    const float* g = &sG[n * 17];
    bool ok = true;
#pragma unroll
    for (int e = 0; e < 4; ++e) {
      float ax = g[e * 4 + 0], ay = g[e * 4 + 1];
      float vx = g[e * 4 + 2], vy = g[e * 4 + 3];
      float c = __fsub_rn(__fmul_rn(vx, __fsub_rn(cy, ay)),
                          __fmul_rn(vy, __fsub_rn(cx, ax)));
      ok = ok && (c >= 0.0f);
    }
    return ok;
  };

  unsigned long long m0 = __ballot(test(lane));
  unsigned long long m1 = __ballot(test(lane + 64));
  int cnt = __popcll(m0) + __popcll(m1);
  floatx4 s = {0.f, 0.f, 0.f, 0.f};
  while (m0) { int n = __builtin_ctzll(m0); m0 &= m0 - 1; s += *(const floatx4*)(obj + n * CC + lane * 4); }
  while (m1) { int n = 64 + __builtin_ctzll(m1); m1 &= m1 - 1; s += *(const floatx4*)(obj + n * CC + lane * 4); }
  float cf = fmaxf((float)cnt, 1.0f);
  short4v o;
#pragma unroll
  for (int j = 0; j < 4; ++j) o[j] = (short)f2bf(__fdiv_rn(s[j], cf));
  *(short4v*)(x0 + cell * CC + lane * 4) = o;
}

// ---------------- conv3x3 256->256 implicit-GEMM MFMA kernel (bf16 NHWC in/out) ----------------
// KW-MAJOR ROW-SHARED schedule (attacks the measured LDS-read bound of R7):
// Block 256 thr = 4 waves; tile = 2 rows x 64 px x 128 co (grid 11x100x2).
// Wave = 2 rows x 64 px x 32 co (tall-wave: B-traffic stays at R7's halved
// level, acc = 64 AGPR, 3 waves/SIMD at __launch_bounds__(256,3)).
// Inner loop runs taps KW-MAJOR (tap order 0,3,6,1,4,7,2,5,8): for one kw, the
// 6 (kh,rr) clusters need halo rows {0,1,1,2,2,3} - rows 1,2 twice. A 3-buffer
// register rotation loads each row ONCE per kw: 12 row-loads/chunk vs 18
// => A-LDS traffic -33% (5.2 GB -> 3.46 GB/dispatch), bank conflicts -33%.
// Death-triggered refill rule: after cluster j, if its A-buffer is dead, load
// row-slot li+3 into the same buffer (gap >= 3 clusters before next use).
// B ring-3 (pairs of 2 frags): prologue loads taps 0,3,6; refill pair p+3 at
// each odd j; the LAST B-load of the chunk (p8 at c11) precedes the DMA issue,
// so no B vmcnt-wait ever forces a mid-chunk drain of the in-flight DMA
// (ds_reads are lgkmcnt - independent of the DMA's vmcnt).
template <bool ADD_RES>
__global__ __launch_bounds__(256, 3) void conv_kernel(
    const u16* __restrict__ in, const u16* __restrict__ wgt,
    const float* __restrict__ bninv, const float* __restrict__ bnbias,
    const u16* __restrict__ res, u16* __restrict__ out) {
  __shared__ u16 sA[2 * 1056 * 8];  // 2 x 16,896 B (4 halo rows x 4 q x 66 px x 16B)

  const int w0 = blockIdx.x * 64;
  const int h0 = blockIdx.y * 2;
  const int tid = threadIdx.x;
  const int lane = tid & 63;
  const int wid = tid >> 6;   // 0..3 = co quarter
  const int ln15 = lane & 15;
  const int quad = lane >> 4;
  const int cg = blockIdx.z * 8 + wid * 2;  // base 16-co group (this wave: cg, cg+1)

  // ---- DMA plan (round-0 proven): 17 wave-issues of 64 slots; wave w owns
  // issues w, w+4, w+8, w+12 (+16 for w=0). slot s = I*64+lane ->
  // r = s/264, q = (s%264)/66, px = s%66; gh = h0+r-1, gw = w0+px-1.
  const u16* ga[5];
  bool gv[5];
#pragma unroll
  for (int j = 0; j < 5; ++j) {
    int I = wid + 4 * j;
    int s = I * 64 + lane;
    int r = s / 264;
    int rem = s - r * 264;
    int q = rem / 66;
    int px = rem - q * 66;
    int gh = h0 + r - 1;
    int gw = w0 + px - 1;
    bool ok = (I <= 16) && (s < 1056) &&
              ((unsigned)gh < (unsigned)HG) && ((unsigned)gw < (unsigned)WGR);
    ga[j] = in + (gh * WGR + gw) * CC + q * 8;  // never dereferenced when !ok
    gv[j] = ok;
    // zero both buffers at geometry-invalid slots (DMA is exec-masked there; stays zero)
    if (I <= 16 && s < 1056 && !ok) {
      short8 z = {};
      *(short8*)(&sA[s * 8]) = z;
      *(short8*)(&sA[(1056 + s) * 8]) = z;
    }
  }

  auto dma = [&](int buf) {
#pragma unroll
    for (int j = 0; j < 5; ++j) {
      int I = wid + 4 * j;
      if (I <= 16) {
        u16* lp = &sA[buf * 8448 + I * 512];  // wave-uniform base; lane writes lp + lane*16B
        if (gv[j])
          __builtin_amdgcn_global_load_lds((guint*)(const void*)ga[j], (luint*)(void*)lp, 16, 0, 0);
      }
      ga[j] += 32;  // advance one ci-chunk (64 B)
    }
  };

  // B-fragment base for this wave: cogrps cg, cg+1
  const u16* wbase = wgt + ((size_t)cg) * 512 + lane * 8;
  auto loadB = [&](int ck, int tap, short8* dst) {
#pragma unroll
    for (int nt = 0; nt < 2; ++nt)
      dst[nt] = *(const short8*)(wbase + ((tap * 8 + ck) * 16 + nt) * 512);
  };

  floatx4 acc0[4][2] = {};  // rr=0 (32 AGPR)
  floatx4 acc1[4][2] = {};  // rr=1 (32 AGPR)
  short8 Ab[3][4];          // 3-row rotation (48 VGPR)
  short8 Bp[3][2];          // B ring-3 of tap pairs (24 VGPR)
  dma(0);  // chunk 0 -> buf 0

  for (int ck = 0; ck < 8; ++ck) {
    const int cur = ck & 1;
    // Barrier: vmcnt drain => chunk-ck DMA landed in buf[cur]; all waves past
    // barrier => done with buf[1-cur].
    __syncthreads();
    // B prologue: tap pairs p0,p1,p2 = taps 0,3,6 (kw=0 column).
    loadB(ck, 0, Bp[0]);
    loadB(ck, 3, Bp[1]);
    loadB(ck, 6, Bp[2]);

    const u16* base = &sA[cur * 8448];
    // A prologue: rows 0,1,2 at kw=0 -> buffers 0,1,2 (load slots L0,L1,L2).
#pragma unroll
    for (int mt = 0; mt < 4; ++mt) {
      Ab[0][mt] = *(const short8*)(base + ((0 * 4 + quad) * 66 + mt * 16 + ln15) * 8);
      Ab[1][mt] = *(const short8*)(base + ((1 * 4 + quad) * 66 + mt * 16 + ln15) * 8);
      Ab[2][mt] = *(const short8*)(base + ((2 * 4 + quad) * 66 + mt * 16 + ln15) * 8);
    }

    // 18 clusters: c = kw*6 + j; j = (kh,rr) in order (0,0)(0,1)(1,0)(1,1)(2,0)(2,1).
    // Load slot li = kw*4 + kh + rr (row = li&3, kw = li>>2, buffer = li%3).
#pragma unroll
    for (int kw = 0; kw < 3; ++kw) {
#pragma unroll
      for (int j = 0; j < 6; ++j) {
        const int kh = j >> 1;
        const int rr = j & 1;
        const int li = kw * 4 + kh + rr;
        const int p = kw * 3 + kh;
        const short8* af = Ab[li % 3];
        const short8* bf = Bp[p % 3];
        __builtin_amdgcn_s_setprio(1);
#pragma unroll
        for (int mt = 0; mt < 4; ++mt)
#pragma unroll
          for (int nt = 0; nt < 2; ++nt) {
            if (rr == 0)
              acc0[mt][nt] = __builtin_amdgcn_mfma_f32_16x16x32_bf16(af[mt], bf[nt], acc0[mt][nt], 0, 0, 0);
            else
              acc1[mt][nt] = __builtin_amdgcn_mfma_f32_16x16x32_bf16(af[mt], bf[nt], acc1[mt][nt], 0, 0, 0);
          }
        __builtin_amdgcn_s_setprio(0);
        // A refill on buffer death (li last used at j=0,2,4,5): load slot li+3
        // into the same buffer ((li+3)%3 == li%3); first use >=3 clusters away.
        if (j == 0 || j == 2 || j == 4 || j == 5) {
          const int ln = li + 3;
          if (ln <= 11) {
            const int r2 = ln & 3;
            const int k2 = ln >> 2;
            const int b2 = ln % 3;
#pragma unroll
            for (int mt = 0; mt < 4; ++mt)
              Ab[b2][mt] = *(const short8*)(base + ((r2 * 4 + quad) * 66 + mt * 16 + ln15 + k2) * 8);
          }
        }
        // B refill on pair death (odd j): pair p+3 (tap = (pn%3)*3 + pn/3).
        if (rr == 1) {
          const int pn = p + 3;
          if (pn <= 8) loadB(ck, (pn % 3) * 3 + pn / 3, Bp[pn % 3]);
        }
        // Next-chunk DMA after the chunk's LAST B-load (c11): no younger
        // same-chunk global load => no mid-chunk vmcnt drain of the DMA;
        // 6 clusters remain to cover ~900cy HBM before the barrier.
        if (kw == 1 && j == 5 && ck < 7) dma(1 - cur);
      }
    }
  }

  float binv_[2], bbia_[2];
#pragma unroll
  for (int nt = 0; nt < 2; ++nt) {
    int co = (cg + nt) * 16 + ln15;
    binv_[nt] = bninv[co];
    bbia_[nt] = bnbias[co];
  }

  // D layout: col(co)=lane&15, row(px)=quad*4+reg
#pragma unroll
  for (int rr = 0; rr < 2; ++rr) {
    const int h = h0 + rr;
#pragma unroll
    for (int mt = 0; mt < 4; ++mt) {
#pragma unroll
      for (int nt = 0; nt < 2; ++nt) {
        int co = (cg + nt) * 16 + ln15;
#pragma unroll
        for (int r = 0; r < 4; ++r) {
          int w = w0 + mt * 16 + quad * 4 + r;
          int idx = (h * WGR + w) * CC + co;
          float v = (rr ? acc1[mt][nt][r] : acc0[mt][nt][r]) * binv_[nt] + bbia_[nt];
          if (ADD_RES) v += bf2f(res[idx]);
          v = fmaxf(v, 0.0f);
          out[idx] = f2bf(v);
        }
      }
    }
  }
}

// ---------------- bf16 NHWC -> fp32 NCHW transpose ----------------
__global__ __launch_bounds__(256) void transpose_kernel(const u16* __restrict__ src, float* __restrict__ dst) {
  __shared__ u16 sT[64][68];
  int w0 = blockIdx.x * 64, h = blockIdx.y, c0 = blockIdx.z * 64;
  int tid = threadIdx.x;
  int cl = (tid & 15) * 4, wl = tid >> 4;
#pragma unroll
  for (int i = 0; i < 4; ++i) {
    int w = wl + i * 16;
    short4v v = *(const short4v*)(src + (h * WGR + w0 + w) * CC + c0 + cl);
    *(short4v*)(&sT[w][cl]) = v;
  }
  __syncthreads();
  int w4 = (tid & 15) * 4, ch = tid >> 4;
#pragma unroll
  for (int i = 0; i < 4; ++i) {
    int c = ch + i * 16;
    floatx4 v;
    v[0] = bf2f(sT[w4 + 0][c]);
    v[1] = bf2f(sT[w4 + 1][c]);
    v[2] = bf2f(sT[w4 + 2][c]);
    v[3] = bf2f(sT[w4 + 3][c]);
    *(floatx4*)(dst + (size_t)(c0 + c) * (HG * WGR) + h * WGR + w0 + w4) = v;
  }
}

extern "C" void kernel_launch(void* const* d_in, const int* in_sizes, int n_in,
                              void* d_out, int out_size, void* d_ws, size_t ws_size,
                              hipStream_t stream) {
  const float* pred_box = (const float*)d_in[0];
  const float* pred_score = (const float*)d_in[1];
  const float* w1 = (const float*)d_in[2];
  const float* b1 = (const float*)d_in[3];
  const float* w2 = (const float*)d_in[4];
  const float* b2 = (const float*)d_in[5];
  const float* w3 = (const float*)d_in[6];
  const float* b3 = (const float*)d_in[7];
  const float* conv_w = (const float*)d_in[8];
  const float* bng = (const float*)d_in[9];
  const float* bnb = (const float*)d_in[10];
  const float* bnm = (const float*)d_in[11];
  const float* bnv = (const float*)d_in[12];

  // Workspace: ~79.3 MB total.
  char* ws = (char*)d_ws;
  u16* W2       = (u16*)(ws);                  // 7,077,888 B packed bf16 weights
  u16* Abuf     = (u16*)(ws + 7077888);        // 72,089,600 B NHWC bf16 activations
  float* obj    = (float*)(ws + 79167488);     // 131,072 B
  float* bninv  = (float*)(ws + 79298560);     // 6,144 B  [6][256]
  float* bnbias = (float*)(ws + 79304704);     // 6,144 B
  float* geo    = (float*)(ws + 79310848);     // 8,192 B  [128][16]
  // d_out (144 MB fp32): first 72 MB doubles as the second bf16 NHWC ping-pong
  // buffer until the final transpose overwrites it with fp32.
  u16* SCR = (u16*)d_out;
  float* OUT = (float*)d_out;

  pack_w_kernel<<<13824, 256, 0, stream>>>(conv_w, W2);
  bn_prep_kernel<<<6, 256, 0, stream>>>(bng, bnb, bnm, bnv, bninv, bnbias);
  box_prep_kernel<<<1, 128, 0, stream>>>(pred_box, geo);
  mlp_kernel<<<NBOX, 256, 0, stream>>>(pred_box, pred_score, w1, b1, w2, b2, w3, b3, obj);
  raster_kernel<<<35200, 256, 0, stream>>>(geo, obj, Abuf);  // x0 -> A

  dim3 cg(11, 100, 2);
  // block0: A -> SCR -> A (res A, in-place)
  conv_kernel<false><<<cg, 256, 0, stream>>>(Abuf, W2 + 0 * 589824, bninv + 0 * 256, bnbias + 0 * 256, nullptr, SCR);
  conv_kernel<true ><<<cg, 256, 0, stream>>>(SCR,  W2 + 1 * 589824, bninv + 1 * 256, bnbias + 1 * 256, Abuf, Abuf);
  // block1: A -> SCR -> A
  conv_kernel<false><<<cg, 256, 0, stream>>>(Abuf, W2 + 2 * 589824, bninv + 2 * 256, bnbias + 2 * 256, nullptr, SCR);
  conv_kernel<true ><<<cg, 256, 0, stream>>>(SCR,  W2 + 3 * 589824, bninv + 3 * 256, bnbias + 3 * 256, Abuf, Abuf);
  // block2: A -> SCR -> A
  conv_kernel<false><<<cg, 256, 0, stream>>>(Abuf, W2 + 4 * 589824, bninv + 4 * 256, bnbias + 4 * 256, nullptr, SCR);
  conv_kernel<true ><<<cg, 256, 0, stream>>>(SCR,  W2 + 5 * 589824, bninv + 5 * 256, bnbias + 5 * 256, Abuf, Abuf);
  // final: bf16 NHWC(A) -> fp32 NCHW(d_out)
  transpose_kernel<<<dim3(11, HG, 4), 256, 0, stream>>>(Abuf, OUT);
}

// Round 9
// 1105.862 us; speedup vs baseline: 1.1445x; 1.1445x over previous
//
#include <hip/hip_runtime.h>

#define HG 200
#define WGR 704
#define CC 256
#define NBOX 128

typedef unsigned short u16;
typedef __attribute__((ext_vector_type(8))) short short8;
typedef __attribute__((ext_vector_type(4))) short short4v;
typedef __attribute__((ext_vector_type(4))) float floatx4;

typedef __attribute__((address_space(1))) const unsigned int guint;
typedef __attribute__((address_space(3))) unsigned int luint;

__device__ __forceinline__ float bf2f(u16 u) {
  unsigned int x = ((unsigned int)u) << 16;
  return __builtin_bit_cast(float, x);
}
__device__ __forceinline__ u16 f2bf(float f) {
  unsigned int x = __builtin_bit_cast(unsigned int, f);
  x += 0x7fffu + ((x >> 16) & 1u);  // round-to-nearest-even
  return (u16)(x >> 16);
}

// ---------------- weight repack + fp32->bf16 ----------------
// Layout (round-0/2 proven): [conv][tap][ck(8)][cogrp(16)][lane(64)][8]:
//   co = cogrp*16 + (l&15), ci = ck*32 + (l>>4)*8 + j
// => a wave's 16co x 32ci B-fragment is ONE contiguous 1KB block (lane*16B).
__global__ __launch_bounds__(256) void pack_w_kernel(const float* __restrict__ cw, u16* __restrict__ W2) {
  int i = blockIdx.x * 256 + threadIdx.x;  // < 6*9*256*256 = 3,538,944
  int conv = i / 589824;
  int r = i - conv * 589824;
  int tap = r / 65536;
  int r2 = r - tap * 65536;
  int ck = r2 >> 13;
  int r3 = r2 & 8191;
  int cogrp = r3 >> 9;
  int r4 = r3 & 511;
  int lane = r4 >> 3;
  int j = r4 & 7;
  int co = cogrp * 16 + (lane & 15);
  int ci = ck * 32 + (lane >> 4) * 8 + j;
  W2[i] = f2bf(cw[((conv * 256 + co) * 256 + ci) * 9 + tap]);
}

// ---------------- BN fold ----------------
__global__ __launch_bounds__(256) void bn_prep_kernel(const float* __restrict__ g, const float* __restrict__ b,
                                                      const float* __restrict__ m, const float* __restrict__ v,
                                                      float* __restrict__ binv, float* __restrict__ bbias) {
  int i = blockIdx.x * 256 + threadIdx.x;  // < 6*256
  float inv = g[i] / sqrtf(v[i] + 1e-5f);
  binv[i] = inv;
  bbias[i] = b[i] - m[i] * inv;
}

// ---------------- box geometry (f32 bit-exact vs reference) ----------------
__global__ __launch_bounds__(128) void box_prep_kernel(const float* __restrict__ pb, float* __restrict__ geo) {
  int b = threadIdx.x;
  float gx[4], gy[4];
#pragma unroll
  for (int j = 0; j < 4; ++j) {
    float px = pb[(b * 8 + j) * 3 + 0];
    float py = pb[(b * 8 + j) * 3 + 1];
    gx[j] = __fdiv_rn(__fsub_rn(px, -140.8f), 0.4f);
    gy[j] = __fdiv_rn(__fsub_rn(py, -40.0f), 0.4f);
  }
  float* g = geo + b * 16;
#pragma unroll
  for (int e = 0; e < 4; ++e) {
    g[e * 4 + 0] = gx[e];
    g[e * 4 + 1] = gy[e];
    g[e * 4 + 2] = __fsub_rn(gx[(e + 1) & 3], gx[e]);
    g[e * 4 + 3] = __fsub_rn(gy[(e + 1) & 3], gy[e]);
  }
}

// ---------------- MLP: one block per box ----------------
__global__ __launch_bounds__(256) void mlp_kernel(
    const float* __restrict__ pb, const float* __restrict__ score,
    const float* __restrict__ w1, const float* __restrict__ b1,
    const float* __restrict__ w2, const float* __restrict__ b2,
    const float* __restrict__ w3, const float* __restrict__ b3,
    float* __restrict__ obj) {
  __shared__ float sf[25];
  __shared__ float h1[256];
  __shared__ float h2[256];
  int b = blockIdx.x, t = threadIdx.x;
  if (t < 24) sf[t] = pb[b * 24 + t];
  if (t == 24) sf[24] = score[b];
  __syncthreads();
  float a = b1[t];
  for (int k = 0; k < 25; ++k) a += sf[k] * w1[k * 256 + t];
  h1[t] = fmaxf(a, 0.0f);
  __syncthreads();
  a = b2[t];
  for (int k = 0; k < 256; ++k) a += h1[k] * w2[k * 256 + t];
  h2[t] = fmaxf(a, 0.0f);
  __syncthreads();
  a = b3[t];
  for (int k = 0; k < 256; ++k) a += h2[k] * w3[k * 256 + t];
  obj[b * 256 + t] = a * score[b];
}

// ---------------- raster (gather): one wave per cell ----------------
__global__ __launch_bounds__(256) void raster_kernel(
    const float* __restrict__ geo, const float* __restrict__ obj, u16* __restrict__ x0) {
  __shared__ float sG[NBOX * 17];
  int tid = threadIdx.x;
  for (int i = tid; i < NBOX * 16; i += 256) sG[(i >> 4) * 17 + (i & 15)] = geo[i];
  __syncthreads();
  int wid = tid >> 6, lane = tid & 63;
  int cell = blockIdx.x * 4 + wid;  // 35200*4 = 140800
  int h = cell / WGR, w = cell - h * WGR;
  float cx = w + 0.5f, cy = h + 0.5f;

  auto test = [&](int n) -> bool {
    const float* g = &sG[n * 17];
    bool ok = true;
#pragma unroll
    for (int e = 0; e < 4; ++e) {
      float ax = g[e * 4 + 0], ay = g[e * 4 + 1];
      float vx = g[e * 4 + 2], vy = g[e * 4 + 3];
      float c = __fsub_rn(__fmul_rn(vx, __fsub_rn(cy, ay)),
                          __fmul_rn(vy, __fsub_rn(cx, ax)));
      ok = ok && (c >= 0.0f);
    }
    return ok;
  };

  unsigned long long m0 = __ballot(test(lane));
  unsigned long long m1 = __ballot(test(lane + 64));
  int cnt = __popcll(m0) + __popcll(m1);
  floatx4 s = {0.f, 0.f, 0.f, 0.f};
  while (m0) { int n = __builtin_ctzll(m0); m0 &= m0 - 1; s += *(const floatx4*)(obj + n * CC + lane * 4); }
  while (m1) { int n = 64 + __builtin_ctzll(m1); m1 &= m1 - 1; s += *(const floatx4*)(obj + n * CC + lane * 4); }
  float cf = fmaxf((float)cnt, 1.0f);
  short4v o;
#pragma unroll
  for (int j = 0; j < 4; ++j) o[j] = (short)f2bf(__fdiv_rn(s[j], cf));
  *(short4v*)(x0 + cell * CC + lane * 4) = o;
}

// ---------------- conv3x3 256->256 implicit-GEMM MFMA kernel (bf16 NHWC in/out) ----------------
// KW-MAJOR ROW-SHARED schedule, LOW-REGISTER variant (R8 spilled; this cuts
// 24 regs from it while keeping the verified -33% LDS-read reduction):
// Block 256 thr = 4 waves; tile = 2 rows x 64 px x 128 co (grid 11x100x2).
// Wave = 2 rows x 64 px x 32 co; acc = 64 AGPR; __launch_bounds__(256,3).
// Within one kw the 6 (kh,rr) clusters need rows r0,r1,r1,r2,r2,r3: a 2-buffer
// X/Y ping-pong (slot rs=kh+rr: even->X, odd->Y) loads each row once per kw
// (12 row-loads/chunk vs 18): X<-r2 after j0 (used j3, gap 2), Y<-r3 after j2
// (used j5, gap 2), X<-r0' after j4 / Y<-r1' after j5 (used next kw, gap 1 -
// ~1 cluster ~ LDS latency, covered by the other 2 waves/SIMD).
// B as ring-2 of PAIRS (pair p=kw*3+kh lives exactly clusters 2p,2p+1): refill
// p+2 on death (gap 2 clusters ~ 260cy > L2 latency). 9 pair-loads/chunk.
// DMA for chunk ck+1 issued after the chunk's LAST B-load (c13): no younger
// B-load waits on it; only the end-of-chunk barrier drain does (~4 clusters
// of cover, A is L2-resident so latency ~300cy).
template <bool ADD_RES>
__global__ __launch_bounds__(256, 3) void conv_kernel(
    const u16* __restrict__ in, const u16* __restrict__ wgt,
    const float* __restrict__ bninv, const float* __restrict__ bnbias,
    const u16* __restrict__ res, u16* __restrict__ out) {
  __shared__ u16 sA[2 * 1056 * 8];  // 2 x 16,896 B (4 halo rows x 4 q x 66 px x 16B)

  const int w0 = blockIdx.x * 64;
  const int h0 = blockIdx.y * 2;
  const int tid = threadIdx.x;
  const int lane = tid & 63;
  const int wid = tid >> 6;   // 0..3 = co quarter
  const int ln15 = lane & 15;
  const int quad = lane >> 4;
  const int cg = blockIdx.z * 8 + wid * 2;  // base 16-co group (this wave: cg, cg+1)

  // ---- DMA plan (round-0 proven): 17 wave-issues of 64 slots; wave w owns
  // issues w, w+4, w+8, w+12 (+16 for w=0). slot s = I*64+lane ->
  // r = s/264, q = (s%264)/66, px = s%66; gh = h0+r-1, gw = w0+px-1.
  const u16* ga[5];
  bool gv[5];
#pragma unroll
  for (int j = 0; j < 5; ++j) {
    int I = wid + 4 * j;
    int s = I * 64 + lane;
    int r = s / 264;
    int rem = s - r * 264;
    int q = rem / 66;
    int px = rem - q * 66;
    int gh = h0 + r - 1;
    int gw = w0 + px - 1;
    bool ok = (I <= 16) && (s < 1056) &&
              ((unsigned)gh < (unsigned)HG) && ((unsigned)gw < (unsigned)WGR);
    ga[j] = in + (gh * WGR + gw) * CC + q * 8;  // never dereferenced when !ok
    gv[j] = ok;
    // zero both buffers at geometry-invalid slots (DMA is exec-masked there; stays zero)
    if (I <= 16 && s < 1056 && !ok) {
      short8 z = {};
      *(short8*)(&sA[s * 8]) = z;
      *(short8*)(&sA[(1056 + s) * 8]) = z;
    }
  }

  auto dma = [&](int buf) {
#pragma unroll
    for (int j = 0; j < 5; ++j) {
      int I = wid + 4 * j;
      if (I <= 16) {
        u16* lp = &sA[buf * 8448 + I * 512];  // wave-uniform base; lane writes lp + lane*16B
        if (gv[j])
          __builtin_amdgcn_global_load_lds((guint*)(const void*)ga[j], (luint*)(void*)lp, 16, 0, 0);
      }
      ga[j] += 32;  // advance one ci-chunk (64 B)
    }
  };

  // B-fragment base for this wave: cogrps cg, cg+1
  const u16* wbase = wgt + ((size_t)cg) * 512 + lane * 8;
  auto loadB = [&](int ck, int tap, short8* dst) {
#pragma unroll
    for (int nt = 0; nt < 2; ++nt)
      dst[nt] = *(const short8*)(wbase + ((tap * 8 + ck) * 16 + nt) * 512);
  };

  floatx4 acc0[4][2] = {};  // rr=0 (32 AGPR)
  floatx4 acc1[4][2] = {};  // rr=1 (32 AGPR)
  short8 Ax[4], Ay[4];      // 2-buffer A row ping-pong (32 VGPR)
  short8 Bp[2][2];          // B ring-2 of tap pairs (16 VGPR)
  dma(0);  // chunk 0 -> buf 0

  for (int ck = 0; ck < 8; ++ck) {
    const int cur = ck & 1;
    // Barrier: vmcnt drain => chunk-ck DMA landed in buf[cur]; all waves past
    // barrier => done with buf[1-cur].
    __syncthreads();
    // B prologue: pairs p0 (tap 0), p1 (tap 3).
    loadB(ck, 0, Bp[0]);
    loadB(ck, 3, Bp[1]);

    const u16* base = &sA[cur * 8448];
    // A prologue: X = row0@kw0, Y = row1@kw0.
#pragma unroll
    for (int mt = 0; mt < 4; ++mt)
      Ax[mt] = *(const short8*)(base + ((0 * 4 + quad) * 66 + mt * 16 + ln15) * 8);
#pragma unroll
    for (int mt = 0; mt < 4; ++mt)
      Ay[mt] = *(const short8*)(base + ((1 * 4 + quad) * 66 + mt * 16 + ln15) * 8);

    // 18 clusters: (kw, j); kh=j>>1, rr=j&1; row slot rs=kh+rr (even->X, odd->Y);
    // B pair p = kw*3+kh held in Bp[p&1].
#pragma unroll
    for (int kw = 0; kw < 3; ++kw) {
#pragma unroll
      for (int j = 0; j < 6; ++j) {
        const int kh = j >> 1;
        const int rr = j & 1;
        const int rs = kh + rr;
        const int p = kw * 3 + kh;
        const short8* af = (rs & 1) ? Ay : Ax;
        const short8* bf = Bp[p & 1];
        __builtin_amdgcn_s_setprio(1);
#pragma unroll
        for (int mt = 0; mt < 4; ++mt)
#pragma unroll
          for (int nt = 0; nt < 2; ++nt) {
            if (rr == 0)
              acc0[mt][nt] = __builtin_amdgcn_mfma_f32_16x16x32_bf16(af[mt], bf[nt], acc0[mt][nt], 0, 0, 0);
            else
              acc1[mt][nt] = __builtin_amdgcn_mfma_f32_16x16x32_bf16(af[mt], bf[nt], acc1[mt][nt], 0, 0, 0);
          }
        __builtin_amdgcn_s_setprio(0);
        // A refills (ds_read, lgkm - independent of the DMA's vmcnt):
        if (j == 0) {  // X <- row2@kw (used j3,j4)
#pragma unroll
          for (int mt = 0; mt < 4; ++mt)
            Ax[mt] = *(const short8*)(base + ((2 * 4 + quad) * 66 + mt * 16 + ln15 + kw) * 8);
        } else if (j == 2) {  // Y <- row3@kw (used j5)
#pragma unroll
          for (int mt = 0; mt < 4; ++mt)
            Ay[mt] = *(const short8*)(base + ((3 * 4 + quad) * 66 + mt * 16 + ln15 + kw) * 8);
        } else if (j == 4 && kw < 2) {  // X <- row0@kw+1 (used next kw j0)
#pragma unroll
          for (int mt = 0; mt < 4; ++mt)
            Ax[mt] = *(const short8*)(base + ((0 * 4 + quad) * 66 + mt * 16 + ln15 + kw + 1) * 8);
        } else if (j == 5 && kw < 2) {  // Y <- row1@kw+1 (used next kw j1)
#pragma unroll
          for (int mt = 0; mt < 4; ++mt)
            Ay[mt] = *(const short8*)(base + ((1 * 4 + quad) * 66 + mt * 16 + ln15 + kw + 1) * 8);
        }
        // B refill on pair death (odd j): pair p+2, tap = (pn%3)*3 + pn/3.
        if (rr == 1) {
          const int pn = p + 2;
          if (pn <= 8) loadB(ck, (pn % 3) * 3 + pn / 3, Bp[pn & 1]);
        }
        // DMA after the chunk's LAST B-load (c13 = kw2,j1): nothing younger
        // waits on it before the barrier; ~4 clusters cover L2-resident A.
        if (kw == 2 && j == 1 && ck < 7) dma(1 - cur);
      }
    }
  }

  float binv_[2], bbia_[2];
#pragma unroll
  for (int nt = 0; nt < 2; ++nt) {
    int co = (cg + nt) * 16 + ln15;
    binv_[nt] = bninv[co];
    bbia_[nt] = bnbias[co];
  }

  // D layout: col(co)=lane&15, row(px)=quad*4+reg
#pragma unroll
  for (int rr = 0; rr < 2; ++rr) {
    const int h = h0 + rr;
#pragma unroll
    for (int mt = 0; mt < 4; ++mt) {
#pragma unroll
      for (int nt = 0; nt < 2; ++nt) {
        int co = (cg + nt) * 16 + ln15;
#pragma unroll
        for (int r = 0; r < 4; ++r) {
          int w = w0 + mt * 16 + quad * 4 + r;
          int idx = (h * WGR + w) * CC + co;
          float v = (rr ? acc1[mt][nt][r] : acc0[mt][nt][r]) * binv_[nt] + bbia_[nt];
          if (ADD_RES) v += bf2f(res[idx]);
          v = fmaxf(v, 0.0f);
          out[idx] = f2bf(v);
        }
      }
    }
  }
}

// ---------------- bf16 NHWC -> fp32 NCHW transpose ----------------
__global__ __launch_bounds__(256) void transpose_kernel(const u16* __restrict__ src, float* __restrict__ dst) {
  __shared__ u16 sT[64][68];
  int w0 = blockIdx.x * 64, h = blockIdx.y, c0 = blockIdx.z * 64;
  int tid = threadIdx.x;
  int cl = (tid & 15) * 4, wl = tid >> 4;
#pragma unroll
  for (int i = 0; i < 4; ++i) {
    int w = wl + i * 16;
    short4v v = *(const short4v*)(src + (h * WGR + w0 + w) * CC + c0 + cl);
    *(short4v*)(&sT[w][cl]) = v;
  }
  __syncthreads();
  int w4 = (tid & 15) * 4, ch = tid >> 4;
#pragma unroll
  for (int i = 0; i < 4; ++i) {
    int c = ch + i * 16;
    floatx4 v;
    v[0] = bf2f(sT[w4 + 0][c]);
    v[1] = bf2f(sT[w4 + 1][c]);
    v[2] = bf2f(sT[w4 + 2][c]);
    v[3] = bf2f(sT[w4 + 3][c]);
    *(floatx4*)(dst + (size_t)(c0 + c) * (HG * WGR) + h * WGR + w0 + w4) = v;
  }
}

extern "C" void kernel_launch(void* const* d_in, const int* in_sizes, int n_in,
                              void* d_out, int out_size, void* d_ws, size_t ws_size,
                              hipStream_t stream) {
  const float* pred_box = (const float*)d_in[0];
  const float* pred_score = (const float*)d_in[1];
  const float* w1 = (const float*)d_in[2];
  const float* b1 = (const float*)d_in[3];
  const float* w2 = (const float*)d_in[4];
  const float* b2 = (const float*)d_in[5];
  const float* w3 = (const float*)d_in[6];
  const float* b3 = (const float*)d_in[7];
  const float* conv_w = (const float*)d_in[8];
  const float* bng = (const float*)d_in[9];
  const float* bnb = (const float*)d_in[10];
  const float* bnm = (const float*)d_in[11];
  const float* bnv = (const float*)d_in[12];

  // Workspace: ~79.3 MB total.
  char* ws = (char*)d_ws;
  u16* W2       = (u16*)(ws);                  // 7,077,888 B packed bf16 weights
  u16* Abuf     = (u16*)(ws + 7077888);        // 72,089,600 B NHWC bf16 activations
  float* obj    = (float*)(ws + 79167488);     // 131,072 B
  float* bninv  = (float*)(ws + 79298560);     // 6,144 B  [6][256]
  float* bnbias = (float*)(ws + 79304704);     // 6,144 B
  float* geo    = (float*)(ws + 79310848);     // 8,192 B  [128][16]
  // d_out (144 MB fp32): first 72 MB doubles as the second bf16 NHWC ping-pong
  // buffer until the final transpose overwrites it with fp32.
  u16* SCR = (u16*)d_out;
  float* OUT = (float*)d_out;

  pack_w_kernel<<<13824, 256, 0, stream>>>(conv_w, W2);
  bn_prep_kernel<<<6, 256, 0, stream>>>(bng, bnb, bnm, bnv, bninv, bnbias);
  box_prep_kernel<<<1, 128, 0, stream>>>(pred_box, geo);
  mlp_kernel<<<NBOX, 256, 0, stream>>>(pred_box, pred_score, w1, b1, w2, b2, w3, b3, obj);
  raster_kernel<<<35200, 256, 0, stream>>>(geo, obj, Abuf);  // x0 -> A

  dim3 cg(11, 100, 2);
  // block0: A -> SCR -> A (res A, in-place)
  conv_kernel<false><<<cg, 256, 0, stream>>>(Abuf, W2 + 0 * 589824, bninv + 0 * 256, bnbias + 0 * 256, nullptr, SCR);
  conv_kernel<true ><<<cg, 256, 0, stream>>>(SCR,  W2 + 1 * 589824, bninv + 1 * 256, bnbias + 1 * 256, Abuf, Abuf);
  // block1: A -> SCR -> A
  conv_kernel<false><<<cg, 256, 0, stream>>>(Abuf, W2 + 2 * 589824, bninv + 2 * 256, bnbias + 2 * 256, nullptr, SCR);
  conv_kernel<true ><<<cg, 256, 0, stream>>>(SCR,  W2 + 3 * 589824, bninv + 3 * 256, bnbias + 3 * 256, Abuf, Abuf);
  // block2: A -> SCR -> A
  conv_kernel<false><<<cg, 256, 0, stream>>>(Abuf, W2 + 4 * 589824, bninv + 4 * 256, bnbias + 4 * 256, nullptr, SCR);
  conv_kernel<true ><<<cg, 256, 0, stream>>>(SCR,  W2 + 5 * 589824, bninv + 5 * 256, bnbias + 5 * 256, Abuf, Abuf);
  // final: bf16 NHWC(A) -> fp32 NCHW(d_out)
  transpose_kernel<<<dim3(11, HG, 4), 256, 0, stream>>>(Abuf, OUT);
}